// Round 7
// baseline (80.587 us; speedup 1.0000x reference)
//
#include <hip/hip_runtime.h>
#include <cmath>

#define Nn 200000
#define Bq 256
#define NWP 512
#define NSEG 391      // ceil(Nn/512)
#define CAP 2048      // per-row compact candidate capacity (typ. bucket ~390)
#define FILL_C 3200000 // float4 per fill chunk (4 chunks = 12.8M = 256*200000/4)

__device__ __forceinline__ bool mask_at(const void* m, size_t idx, int isbyte) {
    if (isbyte) return ((const unsigned char*)m)[idx] != 0;
    return ((const unsigned int*)m)[idx] != 0u;
}

__device__ __forceinline__ void fillz(float4* __restrict__ p, int start4, int end4,
                                      int fb, int nfb) {
    int i = start4 + fb * blockDim.x + threadIdx.x;
    int stride = nfb * blockDim.x;
    const float4 z = make_float4(0.f, 0.f, 0.f, 0.f);
    for (; i < end4; i += stride) p[i] = z;
}

// ---------------- kc1d: seg-hist + mask-format detect + fill chunk 0 ----------------
__global__ __launch_bounds__(512) void kc1d(const int* __restrict__ lib_wp,
                                            int* __restrict__ seg_cnt,
                                            const unsigned int* __restrict__ mw,
                                            int* __restrict__ flag,
                                            float4* __restrict__ fillp) {
    int t = threadIdx.x, bid = blockIdx.x;
    if (bid >= NSEG) {                          // fill role
        fillz(fillp, 0, FILL_C, bid - NSEG, 512);
        return;
    }
    __shared__ int hist[NWP];
    __shared__ int found;
    int seg = bid;
    hist[t] = 0;
    if (t == 0) found = 0;
    __syncthreads();
    if (seg == 0) {
        int f = 0;
        for (int i = t; i < 4096; i += 512) {
            unsigned int w = mw[i];
            if (w >= 2u && w != 0x3F800000u) f = 1;   // byte-packed bools leak into high bytes
        }
        if (f) atomicOr(&found, 1);
    }
    int n = seg * 512 + t;
    if (n < Nn) {
        int w = lib_wp[n]; w = min(max(w, 0), NWP - 1);
        atomicAdd(&hist[w], 1);
    }
    __syncthreads();
    seg_cnt[seg * NWP + t] = hist[t];
    if (seg == 0 && t == 0) flag[0] = found;
}

// ---------------- kc2a: per-waypoint column scan + fill chunk 1 ----------------
__global__ __launch_bounds__(512) void kc2a_colscan(int* __restrict__ seg_cnt,
                                                    int* __restrict__ tot,
                                                    float4* __restrict__ fillp) {
    int t = threadIdx.x, bid = blockIdx.x;
    if (bid >= NWP) {
        fillz(fillp, FILL_C, 2 * FILL_C, bid - NWP, 512);
        return;
    }
    __shared__ int sc[512];
    int w = bid;
    int v = (t < NSEG) ? seg_cnt[t * NWP + w] : 0;
    sc[t] = v;
    __syncthreads();
    for (int off = 1; off < 512; off <<= 1) {
        int x = (t >= off) ? sc[t - off] : 0;
        __syncthreads();
        sc[t] += x;
        __syncthreads();
    }
    if (t < NSEG)
        seg_cnt[t * NWP + w] = (t > 0) ? sc[t - 1] : 0;   // exclusive base
    if (t == 0) tot[w] = sc[NSEG - 1];
}

// ---------------- kc3: offs scan (redundant per block) + stable scatter + fill chunk 2 ----------------
__global__ __launch_bounds__(512) void kc3_scatter(const int* __restrict__ lib_wp,
                                                   const int* __restrict__ seg_cnt,
                                                   const int* __restrict__ tot,
                                                   int* __restrict__ offs_g,
                                                   int* __restrict__ bucket,
                                                   float4* __restrict__ fillp) {
    int t = threadIdx.x, bid = blockIdx.x;
    if (bid >= NSEG) {
        fillz(fillp, 2 * FILL_C, 3 * FILL_C, bid - NSEG, 512);
        return;
    }
    __shared__ int wps[512];
    __shared__ int sc[512];
    // scan waypoint totals -> offsets (each work block redundantly, 9 LDS steps)
    sc[t] = tot[t];
    __syncthreads();
    for (int off = 1; off < 512; off <<= 1) {
        int x = (t >= off) ? sc[t - off] : 0;
        __syncthreads();
        sc[t] += x;
        __syncthreads();
    }
    if (bid == 0) {
        offs_g[t] = (t > 0) ? sc[t - 1] : 0;
        if (t == 0) offs_g[NWP] = sc[NWP - 1];
    }
    int seg = bid;
    int n = seg * 512 + t;
    int w = -1;
    if (n < Nn) { w = lib_wp[n]; w = min(max(w, 0), NWP - 1); }
    wps[t] = w;
    __syncthreads();
    if (n < Nn) {
        int r = 0;
        for (int j = 0; j < t; ++j) r += (wps[j] == w) ? 1 : 0;
        int offw = (w > 0) ? sc[w - 1] : 0;
        bucket[offw + seg_cnt[seg * NWP + w] + r] = n;
    }
}

// ---------------- kA: owner sparse compute (blocks 0..255) + fill chunk 3 ----------------
__global__ __launch_bounds__(256) void kA(
    const float* __restrict__ q, const float* __restrict__ lib, const void* __restrict__ mask,
    const int* __restrict__ wp_id, const int* __restrict__ offs, const int* __restrict__ bucket,
    const int* __restrict__ flag, const float* __restrict__ log_tau,
    float4* __restrict__ fillp, float* __restrict__ pv, float* __restrict__ ctxws,
    int* __restrict__ suff, int* __restrict__ ovfl) {
    int bid = blockIdx.x;
    int t = threadIdx.x;
    if (bid >= 256) {
        fillz(fillp, 3 * FILL_C, 4 * FILL_C, bid - 256, 1024);
        return;
    }
    int b = bid;
    // ---- owner path ----
    __shared__ int   nlist[CAP];
    __shared__ unsigned char vbit[CAP];
    __shared__ float svals[CAP];
    __shared__ float ltile[64 * 65];
    __shared__ float q_s[64];
    __shared__ float red2[256];
    __shared__ int   redc[256];
    __shared__ float pbuf[64];
    __shared__ float Msh, Ssh, scale_sh;

    int isb = flag[0];
    int w = wp_id[b]; w = min(max(w, 0), NWP - 1);
    int off = offs[w], sz = offs[w + 1] - off;
    bool ov = sz > CAP;

    int c = 0;
    if (!ov) {
        for (int i = t; i < sz; i += 256) {
            int n = bucket[off + i];
            nlist[i] = n;
            bool vld = !mask_at(mask, (size_t)b * Nn + n, isb);
            vbit[i] = vld ? 1 : 0;
            c += vld ? 1 : 0;
        }
    } else {
        for (int i = t; i < sz; i += 256) {
            int n = bucket[off + i];
            c += mask_at(mask, (size_t)b * Nn + n, isb) ? 0 : 1;
        }
    }
    redc[t] = c;
    __syncthreads();
    for (int s2 = 128; s2 > 0; s2 >>= 1) {
        if (t < s2) redc[t] += redc[t + s2];
        __syncthreads();
    }
    int cnt = redc[0];
    bool sf = cnt >= 8;
    if (t == 0) { suff[b] = sf ? 1 : 0; ovfl[b] = ov ? 1 : 0; }
    if (!sf || ov) return;            // kB dense-general handles this row

    if (t < 64) q_s[t] = q[b * 64 + t];
    if (t == 0) { Msh = -INFINITY; Ssh = 0.f; }
    float tau = expf(log_tau[0]);
    tau = fminf(fmaxf(tau, 1e-3f), 10.0f);
    float inv_tau = 1.0f / tau;
    int d = t & 63, g = t >> 6;
    float ctxp = 0.f;
    __syncthreads();

    for (int c0 = 0; c0 < sz; c0 += 64) {
        int cn = min(64, sz - c0);
        int i = t >> 2, part = t & 3;
        if (i < cn) {
            int n_i = nlist[c0 + i];
            const float* src = &lib[(size_t)n_i * 64 + part * 16];
            float4 v0 = *(const float4*)&src[0];
            float4 v1 = *(const float4*)&src[4];
            float4 v2 = *(const float4*)&src[8];
            float4 v3 = *(const float4*)&src[12];
            float* dst = &ltile[i * 65 + part * 16];
            dst[0] = v0.x;  dst[1] = v0.y;  dst[2] = v0.z;  dst[3] = v0.w;
            dst[4] = v1.x;  dst[5] = v1.y;  dst[6] = v1.z;  dst[7] = v1.w;
            dst[8] = v2.x;  dst[9] = v2.y;  dst[10] = v2.z; dst[11] = v2.w;
            dst[12] = v3.x; dst[13] = v3.y; dst[14] = v3.z; dst[15] = v3.w;
        }
        __syncthreads();
        float s = -INFINITY;
        if (t < 64) {
            if (t < cn) {
                if (vbit[c0 + t]) {
                    float acc = 0.f;
#pragma unroll
                    for (int dd = 0; dd < 64; ++dd) acc = fmaf(q_s[dd], ltile[t * 65 + dd], acc);
                    s = acc * inv_tau;
                }
                svals[c0 + t] = s;
            }
            float m = s;
#pragma unroll
            for (int o = 1; o < 64; o <<= 1) m = fmaxf(m, __shfl_xor(m, o, 64));
            float e = (s > -INFINITY) ? expf(s - m) : 0.f;
#pragma unroll
            for (int o = 1; o < 64; o <<= 1) e += __shfl_xor(e, o, 64);
            if (t == 0) {
                float newM = fmaxf(Msh, m);
                if (newM > -INFINITY) {
                    float scl = expf(Msh - newM);     // Msh=-inf -> 0 (safe)
                    Ssh = Ssh * scl + e * expf(m - newM);
                    Msh = newM;
                    scale_sh = scl;
                } else {
                    scale_sh = 1.f;
                }
            }
        }
        __syncthreads();
        ctxp *= scale_sh;
        if (t < 64) pbuf[t] = (s > -INFINITY) ? expf(s - Msh) : 0.f;
        __syncthreads();
        for (int i2 = g; i2 < cn; i2 += 4)
            ctxp = fmaf(pbuf[i2], ltile[i2 * 65 + d], ctxp);
        __syncthreads();                  // protect ltile/pbuf/scale_sh reuse
    }
    float M = Msh, invS = 1.0f / Ssh;
    red2[t] = ctxp;
    __syncthreads();
    if (t < 64)
        ctxws[b * 64 + t] = (red2[t] + red2[64 + t] + red2[128 + t] + red2[192 + t]) * invS;
    for (int i = t; i < sz; i += 256) {
        float s2 = svals[i];
        pv[(size_t)b * CAP + i] = (s2 > -INFINITY) ? expf(s2 - M) * invS : 0.f;
    }
}

// ---------------- kB: scatter (or dense-general fallback) + MLP head ----------------
__global__ __launch_bounds__(256) void kB(
    const float* __restrict__ q, const float* __restrict__ lib, const void* __restrict__ mask,
    const int* __restrict__ lib_wp, const int* __restrict__ wp_id,
    const int* __restrict__ offs, const int* __restrict__ bucket,
    const int* __restrict__ flag, const int* __restrict__ suff, const int* __restrict__ ovfl,
    const float* __restrict__ log_tau, const float* __restrict__ pv,
    float* __restrict__ attnbuf, float* __restrict__ ctxws,
    const int* __restrict__ action_id, const float* __restrict__ act_emb,
    const float* __restrict__ W1, const float* __restrict__ b1,
    const float* __restrict__ W2, const float* __restrict__ b2,
    const float* __restrict__ wp_prior, const float* __restrict__ plw,
    float* __restrict__ out) {
    __shared__ float q_s[64];
    __shared__ float redm[4], reds[4];
    __shared__ float Msh, Ssh;
    __shared__ float pbuf2[256];
    int b = blockIdx.x, t = threadIdx.x;
    int sfb = suff[b], ov = ovfl[b];
    int w = wp_id[b]; w = min(max(w, 0), NWP - 1);

    if (sfb && !ov) {
        // sparse scatter of precomputed p over the zero-filled row
        int off = offs[w], sz = offs[w + 1] - off;
        for (int i = t; i < sz; i += 256)
            attnbuf[(size_t)b * Nn + bucket[off + i]] = pv[(size_t)b * CAP + i];
    } else {
        // dense-general evaluator (rare): full reference formula incl. wp filter
        if (t < 64) q_s[t] = q[b * 64 + t];
        if (t == 0) { Msh = -INFINITY; Ssh = 0.f; }
        int isb = flag[0];
        float tau = expf(log_tau[0]);
        tau = fminf(fmaxf(tau, 1e-3f), 10.0f);
        float inv_tau = 1.0f / tau;
        __syncthreads();
        for (int c0 = 0; c0 < Nn; c0 += 256) {
            int n = c0 + t;
            float s = -INFINITY;
            if (n < Nn) {
                bool mk = mask_at(mask, (size_t)b * Nn + n, isb);
                bool wpm = (lib_wp[n] == wp_id[b]);
                if (!mk && !(sfb && !wpm)) {
                    float acc = 0.f;
#pragma unroll
                    for (int dd = 0; dd < 64; dd += 4) {
                        float4 v = *(const float4*)&lib[(size_t)n * 64 + dd];
                        acc = fmaf(q_s[dd], v.x, acc);
                        acc = fmaf(q_s[dd + 1], v.y, acc);
                        acc = fmaf(q_s[dd + 2], v.z, acc);
                        acc = fmaf(q_s[dd + 3], v.w, acc);
                    }
                    s = acc * inv_tau;
                }
                attnbuf[(size_t)b * Nn + n] = s;
            }
            float m = s;
#pragma unroll
            for (int o = 1; o < 64; o <<= 1) m = fmaxf(m, __shfl_xor(m, o, 64));
            float e = (s > -INFINITY) ? expf(s - m) : 0.f;
#pragma unroll
            for (int o = 1; o < 64; o <<= 1) e += __shfl_xor(e, o, 64);
            if ((t & 63) == 0) { redm[t >> 6] = m; reds[t >> 6] = e; }
            __syncthreads();
            if (t == 0) {
                for (int wv = 0; wv < 4; ++wv) {
                    float m2 = redm[wv], e2 = reds[wv];
                    if (m2 > -INFINITY) {
                        if (m2 > Msh) { Ssh = Ssh * expf(Msh - m2) + e2; Msh = m2; }
                        else          { Ssh += e2 * expf(m2 - Msh); }
                    }
                }
            }
            __syncthreads();
        }
        float M = Msh, invS = 1.0f / Ssh;
        int d = t & 63, g = t >> 6;
        float ctxp = 0.f;
        for (int c0 = 0; c0 < Nn; c0 += 256) {
            int n = c0 + t;
            float p = 0.f;
            if (n < Nn) {
                float s = attnbuf[(size_t)b * Nn + n];
                p = (s > -INFINITY) ? expf(s - M) * invS : 0.f;
                attnbuf[(size_t)b * Nn + n] = p;
            }
            pbuf2[t] = p;
            __syncthreads();
            int lim = min(256, Nn - c0);
            for (int i2 = g; i2 < lim; i2 += 4) {
                float p2 = pbuf2[i2];
                if (p2 != 0.f) ctxp = fmaf(p2, lib[(size_t)(c0 + i2) * 64 + d], ctxp);
            }
            __syncthreads();
        }
        pbuf2[t] = ctxp;
        __syncthreads();
        if (t < 64)
            ctxws[b * 64 + t] = pbuf2[t] + pbuf2[64 + t] + pbuf2[128 + t] + pbuf2[192 + t];
    }
    __syncthreads();
    // ---- MLP head + prior (threads 0..63, wave 0) ----
    if (t < 64) {
        int j = t;
        float ctx = ctxws[b * 64 + j];
        float acc = b1[j];
        int aid = action_id[b];
        for (int i = 0; i < 64; ++i) acc = fmaf(q[b * 64 + i], W1[i * 64 + j], acc);
        for (int i = 0; i < 64; ++i) acc = fmaf(__shfl(ctx, i, 64), W1[(64 + i) * 64 + j], acc);
        for (int i = 0; i < 6; ++i) acc = fmaf(act_emb[aid * 6 + i], W1[(128 + i) * 64 + j], acc);
        float h1 = 0.5f * acc * (1.0f + erff(acc * 0.70710678118654752f));
        float v = h1 * W2[j];
#pragma unroll
        for (int o = 1; o < 64; o <<= 1) v += __shfl_xor(v, o, 64);
        if (j == 0) {
            float pr = fminf(fmaxf(wp_prior[b], 1e-3f), 1.0f - 1e-3f);
            float pl = logf(pr) - log1pf(-pr);
            out[b] = v + b2[0] + plw[0] * pl;
        }
    }
}

extern "C" void kernel_launch(void* const* d_in, const int* in_sizes, int n_in,
                              void* d_out, int out_size, void* d_ws, size_t ws_size,
                              hipStream_t stream) {
    const float* q = (const float*)d_in[0];
    const float* lib = (const float*)d_in[1];
    const void* mask = d_in[2];
    const int* lib_wp = (const int*)d_in[3];
    const int* wp_id = (const int*)d_in[4];
    const int* action_id = (const int*)d_in[5];
    const float* wp_prior = (const float*)d_in[6];
    const float* act_emb = (const float*)d_in[7];
    const float* W1 = (const float*)d_in[8];
    const float* b1 = (const float*)d_in[9];
    const float* W2 = (const float*)d_in[10];
    const float* b2 = (const float*)d_in[11];
    const float* log_tau = (const float*)d_in[12];
    const float* plw = (const float*)d_in[13];

    float* out = (float*)d_out;
    float* attnbuf = out + 256;
    float4* fillp = (float4*)attnbuf;        // 16B-aligned (out + 1024 bytes)

    char* ws = (char*)d_ws;
    int* flag    = (int*)(ws + 0);
    int* suff    = (int*)(ws + 1024);        // 256 ints
    int* ovfl    = (int*)(ws + 2048);        // 256 ints
    int* offs    = (int*)(ws + 4096);        // 513 ints
    int* tot     = (int*)(ws + 8192);        // 512 ints
    int* seg_cnt = (int*)(ws + 16384);       // 391*512 ints = 800768 B
    int* bucket  = (int*)(ws + 851968);      // 200000 ints
    float* ctxws = (float*)(ws + 1703936);   // 256*64 floats
    float* pv    = (float*)(ws + 2097152);   // 256*CAP floats = 2 MB

    kc1d<<<dim3(NSEG + 512), 512, 0, stream>>>(lib_wp, seg_cnt,
                                               (const unsigned int*)mask, flag, fillp);
    kc2a_colscan<<<dim3(NWP + 512), 512, 0, stream>>>(seg_cnt, tot, fillp);
    kc3_scatter<<<dim3(NSEG + 512), 512, 0, stream>>>(lib_wp, seg_cnt, tot, offs, bucket,
                                                      fillp);
    kA<<<dim3(256 + 1024), 256, 0, stream>>>(q, lib, mask, wp_id, offs, bucket, flag,
                                             log_tau, fillp, pv, ctxws, suff, ovfl);
    kB<<<dim3(Bq), 256, 0, stream>>>(q, lib, mask, lib_wp, wp_id, offs, bucket, flag, suff,
                                     ovfl, log_tau, pv, attnbuf, ctxws, action_id, act_emb,
                                     W1, b1, W2, b2, wp_prior, plw, out);
}